// Round 6
// baseline (413.762 us; speedup 1.0000x reference)
//
#include <hip/hip_runtime.h>
#include <hip/hip_bf16.h>
#include <cstdint>
#include <cstddef>

#define DM 1024
#define NH 16
#define DKH 64
#define DFF 4096
#define NB 2
#define SQL 2048
#define MROWS (NB * SQL) /* 4096 */
#define QKVN 3072
#define LOG2E 1.44269504088896340736f

typedef __attribute__((ext_vector_type(8))) __bf16 bf16x8;
typedef __attribute__((ext_vector_type(8))) short short8;
typedef __attribute__((ext_vector_type(4))) float f32x4;

__device__ __forceinline__ unsigned short f2bf(float f) {
    unsigned u = __float_as_uint(f);
    u += 0x7fffu + ((u >> 16) & 1u);
    return (unsigned short)(u >> 16);
}
__device__ __forceinline__ unsigned pkbf(float a, float b) {
    __hip_bfloat162 t = __float22bfloat162_rn(make_float2(a, b)); // v_cvt_pk_bf16_f32
    return *reinterpret_cast<unsigned*>(&t);
}
__device__ __forceinline__ bf16x8 ldfrag(const unsigned short* p) {
    return __builtin_bit_cast(bf16x8, *(const short8*)p);
}
__device__ __forceinline__ void gl_lds16(const void* g, void* lds) {
    __builtin_amdgcn_global_load_lds(
        (const __attribute__((address_space(1))) unsigned int*)g,
        (__attribute__((address_space(3))) unsigned int*)lds, 16, 0, 0);
}
#define MFMA16(a, b, c) __builtin_amdgcn_mfma_f32_16x16x32_bf16(a, b, c, 0, 0, 0)

// ---------------- fp32 -> bf16 cast ----------------
__global__ __launch_bounds__(256) void cast_f32_bf16(const float* __restrict__ in,
                                                     unsigned short* __restrict__ out, int n) {
    int i = (blockIdx.x * 256 + threadIdx.x) * 4;
    if (i < n) {
        float4 v = *(const float4*)&in[i];
        ushort4 o;
        o.x = f2bf(v.x); o.y = f2bf(v.y); o.z = f2bf(v.z); o.w = f2bf(v.w);
        *(ushort4*)&out[i] = o;
    }
}

// ---------------- transpose fp32 (K x N) -> bf16 (N x K), optional scale ----------------
__global__ __launch_bounds__(256) void transpose_f32_bf16(const float* __restrict__ in,
                                                          unsigned short* __restrict__ out,
                                                          int K, int N, float scale) {
    __shared__ float tile[32][33];
    const int n0 = blockIdx.x * 32, k0 = blockIdx.y * 32;
    const int tx = threadIdx.x & 31, ty = threadIdx.x >> 5;
#pragma unroll
    for (int i = 0; i < 32; i += 8)
        tile[ty + i][tx] = in[(size_t)(k0 + ty + i) * N + n0 + tx];
    __syncthreads();
#pragma unroll
    for (int i = 0; i < 32; i += 8)
        out[(size_t)(n0 + ty + i) * K + k0 + tx] = f2bf(tile[tx][ty + i] * scale);
}

// ---------------- V transpose: qkv -> vt[bh][d][s] ----------------
__global__ __launch_bounds__(256) void vt_transpose(const unsigned short* __restrict__ qkv,
                                                    unsigned short* __restrict__ vt) {
    __shared__ unsigned short tile[32][33];
    const int s0 = blockIdx.x * 32, d0 = blockIdx.y * 32, bh = blockIdx.z;
    const int b = bh >> 4, h = bh & 15;
    const int tx = threadIdx.x & 31, ty = threadIdx.x >> 5;
#pragma unroll
    for (int i = 0; i < 32; i += 8)
        tile[ty + i][tx] = qkv[(size_t)(b * SQL + s0 + ty + i) * QKVN + 2048 + h * DKH + d0 + tx];
    __syncthreads();
#pragma unroll
    for (int i = 0; i < 32; i += 8)
        vt[(size_t)bh * DKH * SQL + (size_t)(d0 + ty + i) * SQL + s0 + tx] = tile[tx][ty + i];
}

// ---------------- log2(weights + 1e-20) ----------------
__global__ __launch_bounds__(256) void logw_kernel(const float* __restrict__ w,
                                                   float* __restrict__ lw, int n) {
    int i = blockIdx.x * 256 + threadIdx.x;
    if (i < n) lw[i] = log2f(w[i] + 1e-20f);
}

// ---------------- concat bias [bq*0.125*log2e, bk, bv] ----------------
__global__ __launch_bounds__(256) void bqkv_kernel(const float* __restrict__ bq,
                                                   const float* __restrict__ bk,
                                                   const float* __restrict__ bv,
                                                   float* __restrict__ out) {
    int i = blockIdx.x * 256 + threadIdx.x;
    if (i < QKVN)
        out[i] = i < 1024 ? bq[i] * (0.125f * LOG2E) : (i < 2048 ? bk[i - 1024] : bv[i - 2048]);
}

// ---------------- bf16 GEMM: C[M,N] = A[M,K] @ Wt[N,K]^T + bias ----------------
// 128 x BN tile, BK=64, global_load_lds 16B staging, XOR-swizzled 16B blocks.
// KSPL>1: blockIdx.z selects K-slice; fp32 partials at out + z*M*N; bias only z==0.
template <int BN, bool RELU, bool OUT_BF16, int KSPL>
__global__ __launch_bounds__(256) void gemm_kernel(const unsigned short* __restrict__ A,
                                                   const unsigned short* __restrict__ Wt,
                                                   const float* __restrict__ bias,
                                                   void* __restrict__ outp,
                                                   int M, int N, int K) {
    constexpr int NT = BN / 32;
    __shared__ unsigned short As[128 * 64];
    __shared__ unsigned short Bs[BN * 64];
    const int tid = threadIdx.x;
    const int wave = tid >> 6, lane = tid & 63;
    const int col16 = lane & 15, quad = lane >> 4;
    const int lrow = lane >> 3, sblk = (lane & 7) ^ (lrow & 7);
    const int m0 = blockIdx.y * 128, n0 = blockIdx.x * BN;
    const int wm = (wave >> 1) * 64, wn = (wave & 1) * (BN / 2);
    const int kbeg = (KSPL > 1) ? blockIdx.z * (K / KSPL) : 0;
    const int kend = kbeg + K / KSPL;

    f32x4 acc[4][NT] = {};

    for (int k0 = kbeg; k0 < kend; k0 += 64) {
        __syncthreads();
#pragma unroll
        for (int c = wave; c < 16; c += 4)
            gl_lds16(&A[(size_t)(m0 + c * 8 + lrow) * K + k0 + sblk * 8], &As[c * 512]);
#pragma unroll
        for (int c = wave; c < BN / 8; c += 4)
            gl_lds16(&Wt[(size_t)(n0 + c * 8 + lrow) * K + k0 + sblk * 8], &Bs[c * 512]);
        __syncthreads();
#pragma unroll
        for (int kk8 = 0; kk8 < 8; kk8 += 4) {
            bf16x8 af[4], bfr[NT];
#pragma unroll
            for (int t = 0; t < 4; ++t) {
                int R = wm + t * 16 + col16;
                af[t] = ldfrag(&As[R * 64 + (((kk8 + quad) ^ (R & 7)) << 3)]);
            }
#pragma unroll
            for (int t = 0; t < NT; ++t) {
                int R = wn + t * 16 + col16;
                bfr[t] = ldfrag(&Bs[R * 64 + (((kk8 + quad) ^ (R & 7)) << 3)]);
            }
#pragma unroll
            for (int mt = 0; mt < 4; ++mt)
#pragma unroll
                for (int nt = 0; nt < NT; ++nt)
                    acc[mt][nt] = MFMA16(af[mt], bfr[nt], acc[mt][nt]);
        }
    }

    float* outf = (float*)outp + ((KSPL > 1) ? (size_t)blockIdx.z * M * N : 0);
#pragma unroll
    for (int mt = 0; mt < 4; ++mt)
#pragma unroll
        for (int nt = 0; nt < NT; ++nt) {
            int col = n0 + wn + nt * 16 + col16;
            float bv = (KSPL == 1 || blockIdx.z == 0) ? bias[col] : 0.f;
#pragma unroll
            for (int r = 0; r < 4; ++r) {
                int row = m0 + wm + mt * 16 + quad * 4 + r;
                float v = acc[mt][nt][r] + bv;
                if (RELU) v = fmaxf(v, 0.f);
                if (OUT_BF16)
                    ((unsigned short*)outp)[(size_t)row * N + col] = f2bf(v);
                else
                    outf[(size_t)row * N + col] = v;
            }
        }
}

// ---------------- flash attention, split-K over key range ----------------
// grid (SQL/64, NB*NH, 2), block 256. Q pre-scaled by 0.125*log2e; logw in base-2.
// Computes S^T = K @ Q^T so P writes pack 4 consecutive keys per lane (ds_write_b64).
__global__ __launch_bounds__(256) void flash_kernel(const unsigned short* __restrict__ qkv,
                                                    const unsigned short* __restrict__ vt,
                                                    const float* __restrict__ logw,
                                                    float* __restrict__ po,
                                                    float* __restrict__ pl) {
    __shared__ unsigned short Ks[64 * 64];   // swizzled [key][d]
    __shared__ unsigned short Vt[64 * 64];   // swizzled [d][key]
    __shared__ unsigned short Ps[4][16][76]; // per-wave P [q][key]; stride 76 = 8B-aligned, conflict-free
    __shared__ float lws[64];

    const int tid = threadIdx.x, wave = tid >> 6, lane = tid & 63;
    const int col16 = lane & 15, quad = lane >> 4;
    const int lrow = lane >> 3, sblk = (lane & 7) ^ (lrow & 7);
    const int bh = blockIdx.y, b = bh >> 4, h = bh & 15;
    const int q0 = blockIdx.x * 64;
    const int split = blockIdx.z;

    const unsigned short* Kg = qkv + (size_t)b * SQL * QKVN + 1024 + h * DKH;
    const unsigned short* Vg = vt + (size_t)bh * DKH * SQL;

    bf16x8 qf[2];
    {
        const unsigned short* qrow =
            qkv + (size_t)(b * SQL + q0 + wave * 16 + col16) * QKVN + h * DKH;
        qf[0] = ldfrag(qrow + quad * 8);
        qf[1] = ldfrag(qrow + 32 + quad * 8);
    }
    bf16x8 ones;
    {
        short8 o8 = {0x3f80, 0x3f80, 0x3f80, 0x3f80, 0x3f80, 0x3f80, 0x3f80, 0x3f80};
        ones = __builtin_bit_cast(bf16x8, o8);
    }

    f32x4 o[4] = {};
    f32x4 lacc = {};

    for (int kt = split * (SQL / 2); kt < (split + 1) * (SQL / 2); kt += 64) {
        __syncthreads();
#pragma unroll
        for (int c = wave; c < 8; c += 4) {
            gl_lds16(&Kg[(size_t)(kt + c * 8 + lrow) * QKVN + sblk * 8], &Ks[c * 512]);
            gl_lds16(&Vg[(size_t)(c * 8 + lrow) * SQL + kt + sblk * 8], &Vt[c * 512]);
        }
        if (tid < 64) lws[tid] = logw[b * SQL + kt + tid];
        __syncthreads();

        // S^T tile: per nt, rows = 16 keys (lane holds 4 consecutive), cols = 16 q
#pragma unroll
        for (int nt = 0; nt < 4; ++nt) {
            int R = nt * 16 + col16; // key row index for the A-fragment
            f32x4 s4 = {};
            s4 = MFMA16(ldfrag(&Ks[R * 64 + ((quad ^ (R & 7)) << 3)]), qf[0], s4);
            s4 = MFMA16(ldfrag(&Ks[R * 64 + (((4 + quad) ^ (R & 7)) << 3)]), qf[1], s4);
            float4 lw4 = *(const float4*)&lws[nt * 16 + quad * 4];
            float p0 = __builtin_amdgcn_exp2f(s4[0] + lw4.x);
            float p1 = __builtin_amdgcn_exp2f(s4[1] + lw4.y);
            float p2 = __builtin_amdgcn_exp2f(s4[2] + lw4.z);
            float p3 = __builtin_amdgcn_exp2f(s4[3] + lw4.w);
            uint2 packed = {pkbf(p0, p1), pkbf(p2, p3)};
            *(uint2*)&Ps[wave][col16][nt * 16 + quad * 4] = packed; // 4 consecutive keys
        }
        __syncthreads();

        // O^T += V^T P^T ; l += ones . P^T
#pragma unroll
        for (int kk8 = 0; kk8 < 8; kk8 += 4) {
            bf16x8 psf = ldfrag(&Ps[wave][col16][(kk8 + quad) << 3]);
            lacc = MFMA16(ones, psf, lacc);
#pragma unroll
            for (int dt = 0; dt < 4; ++dt) {
                int R = dt * 16 + col16;
                bf16x8 vf = ldfrag(&Vt[R * 64 + (((kk8 + quad) ^ (R & 7)) << 3)]);
                o[dt] = MFMA16(vf, psf, o[dt]);
            }
        }
    }

    const size_t prow = (size_t)(split * 32 + bh) * SQL + q0 + wave * 16 + col16;
#pragma unroll
    for (int dt = 0; dt < 4; ++dt) {
        float4 v4 = {o[dt][0], o[dt][1], o[dt][2], o[dt][3]};
        *(float4*)&po[prow * 64 + dt * 16 + quad * 4] = v4;
    }
    if (quad == 0) pl[prow] = lacc[0];
}

// ---------------- combine split partials -> attn_bf ----------------
__global__ __launch_bounds__(256) void combine_kernel(const float* __restrict__ po,
                                                      const float* __restrict__ pl,
                                                      unsigned short* __restrict__ attn_bf) {
    const int gid = blockIdx.x * 256 + threadIdx.x; // 32*2048*16 threads
    const int t = gid & 15;
    const int row = gid >> 4; // bh*2048 + q
    const int bh = row >> 11, q = row & 2047;
    const int b = bh >> 4, h = bh & 15;
    float4 a = *(const float4*)&po[(size_t)row * 64 + t * 4];
    float4 c = *(const float4*)&po[(size_t)(row + 65536) * 64 + t * 4];
    float rl = 1.f / (pl[row] + pl[row + 65536]);
    ushort4 o;
    o.x = f2bf((a.x + c.x) * rl);
    o.y = f2bf((a.y + c.y) * rl);
    o.z = f2bf((a.z + c.z) * rl);
    o.w = f2bf((a.w + c.w) * rl);
    *(ushort4*)&attn_bf[(size_t)(b * SQL + q) * DM + h * DKH + t * 4] = o;
}

// ---------------- LN1: h = LN(x + d0 + d1); out fp32 + bf16 ----------------
__global__ __launch_bounds__(256) void ln1_kernel(const float* __restrict__ x,
                                                  const float* __restrict__ d0,
                                                  const float* __restrict__ d1,
                                                  const float* __restrict__ g,
                                                  const float* __restrict__ be,
                                                  float* __restrict__ hf,
                                                  unsigned short* __restrict__ hb) {
    const int row = blockIdx.x, tid = threadIdx.x;
    float4 xv = *(const float4*)&x[(size_t)row * DM + tid * 4];
    float4 av = *(const float4*)&d0[(size_t)row * DM + tid * 4];
    float4 bv = *(const float4*)&d1[(size_t)row * DM + tid * 4];
    float v[4] = {xv.x + av.x + bv.x, xv.y + av.y + bv.y, xv.z + av.z + bv.z,
                  xv.w + av.w + bv.w};
    float s = v[0] + v[1] + v[2] + v[3];
    float ss = v[0] * v[0] + v[1] * v[1] + v[2] * v[2] + v[3] * v[3];
#pragma unroll
    for (int m = 1; m < 64; m <<= 1) { s += __shfl_xor(s, m); ss += __shfl_xor(ss, m); }
    __shared__ float sb[4], ssb[4];
    if ((tid & 63) == 0) { sb[tid >> 6] = s; ssb[tid >> 6] = ss; }
    __syncthreads();
    s = sb[0] + sb[1] + sb[2] + sb[3];
    ss = ssb[0] + ssb[1] + ssb[2] + ssb[3];
    float mu = s * (1.f / DM);
    float var = fmaxf(ss * (1.f / DM) - mu * mu, 0.f);
    float rs = rsqrtf(var + 1e-3f);
#pragma unroll
    for (int i = 0; i < 4; ++i) {
        int c = tid * 4 + i;
        float y = (v[i] - mu) * rs * g[c] + be[c];
        hf[(size_t)row * DM + c] = y;
        hb[(size_t)row * DM + c] = f2bf(y);
    }
}

// ---------------- LN2: out = LN(h + d0 + d1) fp32 ----------------
__global__ __launch_bounds__(256) void ln2_kernel(const float* __restrict__ hf,
                                                  const float* __restrict__ d0,
                                                  const float* __restrict__ d1,
                                                  const float* __restrict__ g,
                                                  const float* __restrict__ be,
                                                  float* __restrict__ outp) {
    const int row = blockIdx.x, tid = threadIdx.x;
    float4 hv = *(const float4*)&hf[(size_t)row * DM + tid * 4];
    float4 av = *(const float4*)&d0[(size_t)row * DM + tid * 4];
    float4 bv = *(const float4*)&d1[(size_t)row * DM + tid * 4];
    float v[4] = {hv.x + av.x + bv.x, hv.y + av.y + bv.y, hv.z + av.z + bv.z,
                  hv.w + av.w + bv.w};
    float s = v[0] + v[1] + v[2] + v[3];
    float ss = v[0] * v[0] + v[1] * v[1] + v[2] * v[2] + v[3] * v[3];
#pragma unroll
    for (int m = 1; m < 64; m <<= 1) { s += __shfl_xor(s, m); ss += __shfl_xor(ss, m); }
    __shared__ float sb[4], ssb[4];
    if ((tid & 63) == 0) { sb[tid >> 6] = s; ssb[tid >> 6] = ss; }
    __syncthreads();
    s = sb[0] + sb[1] + sb[2] + sb[3];
    ss = ssb[0] + ssb[1] + ssb[2] + ssb[3];
    float mu = s * (1.f / DM);
    float var = fmaxf(ss * (1.f / DM) - mu * mu, 0.f);
    float rs = rsqrtf(var + 1e-3f);
    float4 ov;
    ov.x = (v[0] - mu) * rs * g[tid * 4 + 0] + be[tid * 4 + 0];
    ov.y = (v[1] - mu) * rs * g[tid * 4 + 1] + be[tid * 4 + 1];
    ov.z = (v[2] - mu) * rs * g[tid * 4 + 2] + be[tid * 4 + 2];
    ov.w = (v[3] - mu) * rs * g[tid * 4 + 3] + be[tid * 4 + 3];
    *(float4*)&outp[(size_t)row * DM + tid * 4] = ov;
}

extern "C" void kernel_launch(void* const* d_in, const int* in_sizes, int n_in,
                              void* d_out, int out_size, void* d_ws, size_t ws_size,
                              hipStream_t stream) {
    const float* x   = (const float*)d_in[0];
    const float* wts = (const float*)d_in[1];
    const float* Wq  = (const float*)d_in[2];
    const float* bq  = (const float*)d_in[3];
    const float* Wk  = (const float*)d_in[4];
    const float* bk  = (const float*)d_in[5];
    const float* Wv  = (const float*)d_in[6];
    const float* bv  = (const float*)d_in[7];
    const float* Wo  = (const float*)d_in[8];
    const float* bo  = (const float*)d_in[9];
    const float* W1  = (const float*)d_in[10];
    const float* b1  = (const float*)d_in[11];
    const float* W2  = (const float*)d_in[12];
    const float* b2  = (const float*)d_in[13];
    const float* g1  = (const float*)d_in[14];
    const float* be1 = (const float*)d_in[15];
    const float* g2  = (const float*)d_in[16];
    const float* be2 = (const float*)d_in[17];

    char* ws = (char*)d_ws;
    const size_t MB = 1u << 20;
    // Arena timeline (peak ~98.6 MB) — identical to R5 (verified no alias hazards):
    unsigned short* qkv_bf  = (unsigned short*)(ws + 0 * MB);
    unsigned short* vt      = (unsigned short*)(ws + 24 * MB);
    unsigned short* x_bf    = (unsigned short*)(ws + 32 * MB);
    unsigned short* wqkv_t  = (unsigned short*)(ws + 40 * MB);
    unsigned short* Wo_t    = (unsigned short*)(ws + 46 * MB);
    unsigned short* W1_t    = (unsigned short*)(ws + 48 * MB);
    float* po               = (float*)(ws + 64 * MB);
    unsigned short* W2_t    = (unsigned short*)(ws + 88 * MB);
    float* pl               = (float*)(ws + 98 * MB);
    float* bqkv             = (float*)(ws + 98 * MB + 0x80000);
    float* logw             = (float*)(ws + 98 * MB + 0x88000);
    unsigned short* attn_bf = (unsigned short*)(ws + 32 * MB);
    float* attnproj         = (float*)(ws + 0 * MB);   // partials [0,16),[16,32)
    float* h_f32            = (float*)(ws + 64 * MB);
    unsigned short* h_bf    = (unsigned short*)(ws + 80 * MB);
    unsigned short* ffn1_bf = (unsigned short*)(ws + 0 * MB);
    float* ffn2             = (float*)(ws + 32 * MB);  // partials [32,48),[48,64)

    // 1. prep (W2 transpose deferred until po is dead)
    cast_f32_bf16<<<(MROWS * DM) / 1024, 256, 0, stream>>>(x, x_bf, MROWS * DM);
    transpose_f32_bf16<<<dim3(32, 32), 256, 0, stream>>>(Wq, wqkv_t, DM, DM, 0.125f * LOG2E);
    transpose_f32_bf16<<<dim3(32, 32), 256, 0, stream>>>(Wk, wqkv_t + (size_t)1024 * DM, DM, DM, 1.f);
    transpose_f32_bf16<<<dim3(32, 32), 256, 0, stream>>>(Wv, wqkv_t + (size_t)2048 * DM, DM, DM, 1.f);
    transpose_f32_bf16<<<dim3(32, 32), 256, 0, stream>>>(Wo, Wo_t, DM, DM, 1.f);
    transpose_f32_bf16<<<dim3(128, 32), 256, 0, stream>>>(W1, W1_t, DM, DFF, 1.f);
    bqkv_kernel<<<12, 256, 0, stream>>>(bq, bk, bv, bqkv);
    logw_kernel<<<(MROWS + 255) / 256, 256, 0, stream>>>(wts, logw, MROWS);

    // 2. fused QKV projection
    gemm_kernel<128, false, true, 1><<<dim3(QKVN / 128, MROWS / 128), 256, 0, stream>>>(
        x_bf, wqkv_t, bqkv, qkv_bf, MROWS, QKVN, DM);

    // 3. attention (split-K over keys) + combine
    vt_transpose<<<dim3(SQL / 32, DKH / 32, NB * NH), 256, 0, stream>>>(qkv_bf, vt);
    flash_kernel<<<dim3(SQL / 64, NB * NH, 2), 256, 0, stream>>>(qkv_bf, vt, logw, po, pl);
    combine_kernel<<<(32 * 2048 * 16) / 256, 256, 0, stream>>>(po, pl, attn_bf);

    // W2 transpose now that po ([64,98)) is dead; target [88,96)
    transpose_f32_bf16<<<dim3(32, 128), 256, 0, stream>>>(W2, W2_t, DFF, DM, 1.f);

    // 4. O projection (split-K 2) + LN1
    gemm_kernel<64, false, false, 2><<<dim3(DM / 64, MROWS / 128, 2), 256, 0, stream>>>(
        attn_bf, Wo_t, bo, attnproj, MROWS, DM, DM);
    ln1_kernel<<<MROWS, 256, 0, stream>>>(x, attnproj, attnproj + (size_t)MROWS * DM,
                                          g1, be1, h_f32, h_bf);

    // 5. FFN (FFN2 split-K 2) + LN2
    gemm_kernel<128, true, true, 1><<<dim3(DFF / 128, MROWS / 128), 256, 0, stream>>>(
        h_bf, W1_t, b1, ffn1_bf, MROWS, DFF, DM);
    gemm_kernel<64, false, false, 2><<<dim3(DM / 64, MROWS / 128, 2), 256, 0, stream>>>(
        ffn1_bf, W2_t, b2, ffn2, MROWS, DM, DFF);
    ln2_kernel<<<MROWS, 256, 0, stream>>>(h_f32, ffn2, ffn2 + (size_t)MROWS * DM,
                                          g2, be2, (float*)d_out);
}

// Round 7
// 386.049 us; speedup vs baseline: 1.0718x; 1.0718x over previous
//
#include <hip/hip_runtime.h>
#include <cstdint>
#include <cstddef>

#define DM 1024
#define NH 16
#define DKH 64
#define DFF 4096
#define NB 2
#define SQL 2048
#define MROWS (NB * SQL) /* 4096 */
#define QKVN 3072

typedef __attribute__((ext_vector_type(8))) __bf16 bf16x8;
typedef __attribute__((ext_vector_type(8))) short short8;
typedef __attribute__((ext_vector_type(4))) float f32x4;

__device__ __forceinline__ unsigned short f2bf(float f) {
    unsigned u = __float_as_uint(f);
    u += 0x7fffu + ((u >> 16) & 1u);
    return (unsigned short)(u >> 16);
}
__device__ __forceinline__ bf16x8 ldfrag(const unsigned short* p) {
    return __builtin_bit_cast(bf16x8, *(const short8*)p);
}
__device__ __forceinline__ void gl_lds16(const void* g, void* lds) {
    __builtin_amdgcn_global_load_lds(
        (const __attribute__((address_space(1))) unsigned int*)g,
        (__attribute__((address_space(3))) unsigned int*)lds, 16, 0, 0);
}
#define MFMA16(a, b, c) __builtin_amdgcn_mfma_f32_16x16x32_bf16(a, b, c, 0, 0, 0)

// ---------------- merged misc prep: x cast (4096 blks) + logw (16) + bqkv (12) ----------------
__global__ __launch_bounds__(256) void prep_misc(const float* __restrict__ x,
                                                 const float* __restrict__ wts,
                                                 const float* __restrict__ bq,
                                                 const float* __restrict__ bk,
                                                 const float* __restrict__ bv,
                                                 unsigned short* __restrict__ x_bf,
                                                 float* __restrict__ logw,
                                                 float* __restrict__ bqkv) {
    const int bid = blockIdx.x, tid = threadIdx.x;
    if (bid < 4096) {
        int i = (bid * 256 + tid) * 4;
        float4 v = *(const float4*)&x[i];
        ushort4 o;
        o.x = f2bf(v.x); o.y = f2bf(v.y); o.z = f2bf(v.z); o.w = f2bf(v.w);
        *(ushort4*)&x_bf[i] = o;
    } else if (bid < 4112) {
        int i = (bid - 4096) * 256 + tid;
        logw[i] = logf(wts[i] + 1e-20f);
    } else {
        int i = (bid - 4112) * 256 + tid;
        if (i < QKVN)
            bqkv[i] = i < 1024 ? bq[i] * 0.125f : (i < 2048 ? bk[i - 1024] : bv[i - 2048]);
    }
}

// ---------------- merged weight transposes: fp32 (K x N) -> bf16 (N x K) ----------------
// blocks [0,1024) Wq (scale 1/8), [1024,2048) Wk, [2048,3072) Wv, [3072,4096) Wo, [4096,8192) W1
__global__ __launch_bounds__(256) void prep_weights(const float* __restrict__ Wq,
                                                    const float* __restrict__ Wk,
                                                    const float* __restrict__ Wv,
                                                    const float* __restrict__ Wo,
                                                    const float* __restrict__ W1,
                                                    unsigned short* __restrict__ wqkv_t,
                                                    unsigned short* __restrict__ Wo_t,
                                                    unsigned short* __restrict__ W1_t) {
    __shared__ float tile[32][33];
    const int t = blockIdx.x;
    const float* in;
    unsigned short* out;
    int K = DM, N = DM, n0, k0;
    float scale = 1.f;
    if (t < 1024)      { in = Wq; out = wqkv_t;                      scale = 0.125f;
                         n0 = (t & 31) * 32;          k0 = (t >> 5) * 32; }
    else if (t < 2048) { in = Wk; out = wqkv_t + (size_t)1024 * DM;
                         n0 = ((t - 1024) & 31) * 32; k0 = ((t - 1024) >> 5) * 32; }
    else if (t < 3072) { in = Wv; out = wqkv_t + (size_t)2048 * DM;
                         n0 = ((t - 2048) & 31) * 32; k0 = ((t - 2048) >> 5) * 32; }
    else if (t < 4096) { in = Wo; out = Wo_t;
                         n0 = ((t - 3072) & 31) * 32; k0 = ((t - 3072) >> 5) * 32; }
    else               { in = W1; out = W1_t; N = DFF;
                         n0 = ((t - 4096) & 127) * 32; k0 = ((t - 4096) >> 7) * 32; }
    const int tx = threadIdx.x & 31, ty = threadIdx.x >> 5;
#pragma unroll
    for (int i = 0; i < 32; i += 8)
        tile[ty + i][tx] = in[(size_t)(k0 + ty + i) * N + n0 + tx];
    __syncthreads();
#pragma unroll
    for (int i = 0; i < 32; i += 8)
        out[(size_t)(n0 + ty + i) * K + k0 + tx] = f2bf(tile[tx][ty + i] * scale);
}

// ---------------- standalone transpose (for deferred W2) ----------------
__global__ __launch_bounds__(256) void transpose_f32_bf16(const float* __restrict__ in,
                                                          unsigned short* __restrict__ out,
                                                          int K, int N, float scale) {
    __shared__ float tile[32][33];
    const int n0 = blockIdx.x * 32, k0 = blockIdx.y * 32;
    const int tx = threadIdx.x & 31, ty = threadIdx.x >> 5;
#pragma unroll
    for (int i = 0; i < 32; i += 8)
        tile[ty + i][tx] = in[(size_t)(k0 + ty + i) * N + n0 + tx];
    __syncthreads();
#pragma unroll
    for (int i = 0; i < 32; i += 8)
        out[(size_t)(n0 + ty + i) * K + k0 + tx] = f2bf(tile[tx][ty + i] * scale);
}

// ---------------- bf16 GEMM: C[M,N] = A[M,K] @ Wt[N,K]^T + bias ----------------
// 128 x BN tile, BK=64, global_load_lds 16B staging, XOR-swizzled 16B blocks.
// OMODE: 0 = fp32 partials (out + z*M*N), 1 = bf16 row-major, 2 = bf16 row-major for
//        col<2048 and V-transposed (vt[bh][d][s]) for col>=2048 (QKV fused epilogue).
template <int BN, bool RELU, int OMODE, int KSPL>
__global__ __launch_bounds__(256) void gemm_kernel(const unsigned short* __restrict__ A,
                                                   const unsigned short* __restrict__ Wt,
                                                   const float* __restrict__ bias,
                                                   void* __restrict__ outp,
                                                   unsigned short* __restrict__ vtp,
                                                   int M, int N, int K) {
    constexpr int NT = BN / 32;
    __shared__ unsigned short As[128 * 64];
    __shared__ unsigned short Bs[BN * 64];
    const int tid = threadIdx.x;
    const int wave = tid >> 6, lane = tid & 63;
    const int col16 = lane & 15, quad = lane >> 4;
    const int lrow = lane >> 3, sblk = (lane & 7) ^ (lrow & 7);
    const int m0 = blockIdx.y * 128, n0 = blockIdx.x * BN;
    const int wm = (wave >> 1) * 64, wn = (wave & 1) * (BN / 2);
    const int kbeg = (KSPL > 1) ? blockIdx.z * (K / KSPL) : 0;
    const int kend = kbeg + K / KSPL;

    f32x4 acc[4][NT] = {};

    for (int k0 = kbeg; k0 < kend; k0 += 64) {
        __syncthreads();
#pragma unroll
        for (int c = wave; c < 16; c += 4)
            gl_lds16(&A[(size_t)(m0 + c * 8 + lrow) * K + k0 + sblk * 8], &As[c * 512]);
#pragma unroll
        for (int c = wave; c < BN / 8; c += 4)
            gl_lds16(&Wt[(size_t)(n0 + c * 8 + lrow) * K + k0 + sblk * 8], &Bs[c * 512]);
        __syncthreads();
#pragma unroll
        for (int kk8 = 0; kk8 < 8; kk8 += 4) {
            bf16x8 af[4], bfr[NT];
#pragma unroll
            for (int t = 0; t < 4; ++t) {
                int R = wm + t * 16 + col16;
                af[t] = ldfrag(&As[R * 64 + (((kk8 + quad) ^ (R & 7)) << 3)]);
            }
#pragma unroll
            for (int t = 0; t < NT; ++t) {
                int R = wn + t * 16 + col16;
                bfr[t] = ldfrag(&Bs[R * 64 + (((kk8 + quad) ^ (R & 7)) << 3)]);
            }
#pragma unroll
            for (int mt = 0; mt < 4; ++mt)
#pragma unroll
                for (int nt = 0; nt < NT; ++nt)
                    acc[mt][nt] = MFMA16(af[mt], bfr[nt], acc[mt][nt]);
        }
    }

    float* outf = (float*)outp + ((KSPL > 1) ? (size_t)blockIdx.z * M * N : 0);
#pragma unroll
    for (int mt = 0; mt < 4; ++mt)
#pragma unroll
        for (int nt = 0; nt < NT; ++nt) {
            int col = n0 + wn + nt * 16 + col16;
            float bv = (KSPL == 1 || blockIdx.z == 0) ? bias[col] : 0.f;
            if (OMODE == 2 && col >= 2048) {
                // V tile: write transposed into vt[bh][d][s], packed over 4 consecutive s
                int dl = (col - 2048) & 63, hh = (col - 2048) >> 6;
                int row0 = m0 + wm + mt * 16 + quad * 4;
                int bb = row0 >> 11, sb = row0 & 2047;
                ushort4 w4;
                w4.x = f2bf(acc[mt][nt][0] + bv);
                w4.y = f2bf(acc[mt][nt][1] + bv);
                w4.z = f2bf(acc[mt][nt][2] + bv);
                w4.w = f2bf(acc[mt][nt][3] + bv);
                *(ushort4*)&vtp[(size_t)(bb * NH + hh) * DKH * SQL + (size_t)dl * SQL + sb] = w4;
            } else {
#pragma unroll
                for (int r = 0; r < 4; ++r) {
                    int row = m0 + wm + mt * 16 + quad * 4 + r;
                    float v = acc[mt][nt][r] + bv;
                    if (RELU) v = fmaxf(v, 0.f);
                    if (OMODE == 0)
                        outf[(size_t)row * N + col] = v;
                    else
                        ((unsigned short*)outp)[(size_t)row * N + col] = f2bf(v);
                }
            }
        }
}

// ---------------- flash attention, split-K over key range (R5-verified body) ----------------
// grid (SQL/64, NB*NH, 2 splits), block 256. Q pre-scaled 1/8. Writes fp32 partials.
__global__ __launch_bounds__(256) void flash_kernel(const unsigned short* __restrict__ qkv,
                                                    const unsigned short* __restrict__ vt,
                                                    const float* __restrict__ logw,
                                                    float* __restrict__ po,
                                                    float* __restrict__ pl) {
    __shared__ unsigned short Ks[64 * 64];
    __shared__ unsigned short Vt[64 * 64];
    __shared__ unsigned short Ps[4][16][72];
    __shared__ float lws[64];

    const int tid = threadIdx.x, wave = tid >> 6, lane = tid & 63;
    const int col16 = lane & 15, quad = lane >> 4;
    const int lrow = lane >> 3, sblk = (lane & 7) ^ (lrow & 7);
    const int bh = blockIdx.y, b = bh >> 4, h = bh & 15;
    const int q0 = blockIdx.x * 64;
    const int split = blockIdx.z;

    const unsigned short* Kg = qkv + (size_t)b * SQL * QKVN + 1024 + h * DKH;
    const unsigned short* Vg = vt + (size_t)bh * DKH * SQL;

    bf16x8 qf[2];
    {
        const unsigned short* qrow =
            qkv + (size_t)(b * SQL + q0 + wave * 16 + col16) * QKVN + h * DKH;
        qf[0] = ldfrag(qrow + quad * 8);
        qf[1] = ldfrag(qrow + 32 + quad * 8);
    }
    bf16x8 ones;
    {
        short8 o8 = {0x3f80, 0x3f80, 0x3f80, 0x3f80, 0x3f80, 0x3f80, 0x3f80, 0x3f80};
        ones = __builtin_bit_cast(bf16x8, o8);
    }

    f32x4 o[4] = {};
    f32x4 lacc = {};

    for (int kt = split * (SQL / 2); kt < (split + 1) * (SQL / 2); kt += 64) {
        __syncthreads();
#pragma unroll
        for (int c = wave; c < 8; c += 4) {
            gl_lds16(&Kg[(size_t)(kt + c * 8 + lrow) * QKVN + sblk * 8], &Ks[c * 512]);
            gl_lds16(&Vg[(size_t)(c * 8 + lrow) * SQL + kt + sblk * 8], &Vt[c * 512]);
        }
        if (tid < 64) lws[tid] = logw[b * SQL + kt + tid];
        __syncthreads();

        float pv[4][4];
#pragma unroll
        for (int nt = 0; nt < 4; ++nt) {
            int R = nt * 16 + col16;
            f32x4 s4 = {};
            s4 = MFMA16(qf[0], ldfrag(&Ks[R * 64 + ((quad ^ (R & 7)) << 3)]), s4);
            s4 = MFMA16(qf[1], ldfrag(&Ks[R * 64 + (((4 + quad) ^ (R & 7)) << 3)]), s4);
            float lw = lws[R];
#pragma unroll
            for (int r = 0; r < 4; ++r) pv[nt][r] = __expf(s4[r] + lw);
        }
#pragma unroll
        for (int nt = 0; nt < 4; ++nt)
#pragma unroll
            for (int r = 0; r < 4; ++r)
                Ps[wave][quad * 4 + r][nt * 16 + col16] = f2bf(pv[nt][r]);
        __syncthreads();

#pragma unroll
        for (int kk8 = 0; kk8 < 8; kk8 += 4) {
            bf16x8 psf = ldfrag(&Ps[wave][col16][(kk8 + quad) << 3]);
            lacc = MFMA16(ones, psf, lacc);
#pragma unroll
            for (int dt = 0; dt < 4; ++dt) {
                int R = dt * 16 + col16;
                bf16x8 vf = ldfrag(&Vt[R * 64 + (((kk8 + quad) ^ (R & 7)) << 3)]);
                o[dt] = MFMA16(vf, psf, o[dt]);
            }
        }
    }

    const size_t prow = (size_t)(split * 32 + bh) * SQL + q0 + wave * 16 + col16;
#pragma unroll
    for (int dt = 0; dt < 4; ++dt) {
        float4 v4 = {o[dt][0], o[dt][1], o[dt][2], o[dt][3]};
        *(float4*)&po[prow * 64 + dt * 16 + quad * 4] = v4;
    }
    if (quad == 0) pl[prow] = lacc[0];
}

// ---------------- combine split partials -> attn_bf ----------------
__global__ __launch_bounds__(256) void combine_kernel(const float* __restrict__ po,
                                                      const float* __restrict__ pl,
                                                      unsigned short* __restrict__ attn_bf) {
    const int gid = blockIdx.x * 256 + threadIdx.x; // 32*2048*16 threads
    const int t = gid & 15;
    const int row = gid >> 4; // bh*2048 + q
    const int bh = row >> 11, q = row & 2047;
    const int b = bh >> 4, h = bh & 15;
    float4 a = *(const float4*)&po[(size_t)row * 64 + t * 4];
    float4 c = *(const float4*)&po[(size_t)(row + 65536) * 64 + t * 4];
    float rl = 1.f / (pl[row] + pl[row + 65536]);
    ushort4 o;
    o.x = f2bf((a.x + c.x) * rl);
    o.y = f2bf((a.y + c.y) * rl);
    o.z = f2bf((a.z + c.z) * rl);
    o.w = f2bf((a.w + c.w) * rl);
    *(ushort4*)&attn_bf[(size_t)(b * SQL + q) * DM + h * DKH + t * 4] = o;
}

// ---------------- LN1: h = LN(x + d0 + d1); out fp32 + bf16 ----------------
__global__ __launch_bounds__(256) void ln1_kernel(const float* __restrict__ x,
                                                  const float* __restrict__ d0,
                                                  const float* __restrict__ d1,
                                                  const float* __restrict__ g,
                                                  const float* __restrict__ be,
                                                  float* __restrict__ hf,
                                                  unsigned short* __restrict__ hb) {
    const int row = blockIdx.x, tid = threadIdx.x;
    float4 xv = *(const float4*)&x[(size_t)row * DM + tid * 4];
    float4 av = *(const float4*)&d0[(size_t)row * DM + tid * 4];
    float4 bv = *(const float4*)&d1[(size_t)row * DM + tid * 4];
    float v[4] = {xv.x + av.x + bv.x, xv.y + av.y + bv.y, xv.z + av.z + bv.z,
                  xv.w + av.w + bv.w};
    float s = v[0] + v[1] + v[2] + v[3];
    float ss = v[0] * v[0] + v[1] * v[1] + v[2] * v[2] + v[3] * v[3];
#pragma unroll
    for (int m = 1; m < 64; m <<= 1) { s += __shfl_xor(s, m); ss += __shfl_xor(ss, m); }
    __shared__ float sb[4], ssb[4];
    if ((tid & 63) == 0) { sb[tid >> 6] = s; ssb[tid >> 6] = ss; }
    __syncthreads();
    s = sb[0] + sb[1] + sb[2] + sb[3];
    ss = ssb[0] + ssb[1] + ssb[2] + ssb[3];
    float mu = s * (1.f / DM);
    float var = fmaxf(ss * (1.f / DM) - mu * mu, 0.f);
    float rs = rsqrtf(var + 1e-3f);
#pragma unroll
    for (int i = 0; i < 4; ++i) {
        int c = tid * 4 + i;
        float y = (v[i] - mu) * rs * g[c] + be[c];
        hf[(size_t)row * DM + c] = y;
        hb[(size_t)row * DM + c] = f2bf(y);
    }
}

// ---------------- LN2: out = LN(h + d0 + d1) fp32 ----------------
__global__ __launch_bounds__(256) void ln2_kernel(const float* __restrict__ hf,
                                                  const float* __restrict__ d0,
                                                  const float* __restrict__ d1,
                                                  const float* __restrict__ g,
                                                  const float* __restrict__ be,
                                                  float* __restrict__ outp) {
    const int row = blockIdx.x, tid = threadIdx.x;
    float4 hv = *(const float4*)&hf[(size_t)row * DM + tid * 4];
    float4 av = *(const float4*)&d0[(size_t)row * DM + tid * 4];
    float4 bv = *(const float4*)&d1[(size_t)row * DM + tid * 4];
    float v[4] = {hv.x + av.x + bv.x, hv.y + av.y + bv.y, hv.z + av.z + bv.z,
                  hv.w + av.w + bv.w};
    float s = v[0] + v[1] + v[2] + v[3];
    float ss = v[0] * v[0] + v[1] * v[1] + v[2] * v[2] + v[3] * v[3];
#pragma unroll
    for (int m = 1; m < 64; m <<= 1) { s += __shfl_xor(s, m); ss += __shfl_xor(ss, m); }
    __shared__ float sb[4], ssb[4];
    if ((tid & 63) == 0) { sb[tid >> 6] = s; ssb[tid >> 6] = ss; }
    __syncthreads();
    s = sb[0] + sb[1] + sb[2] + sb[3];
    ss = ssb[0] + ssb[1] + ssb[2] + ssb[3];
    float mu = s * (1.f / DM);
    float var = fmaxf(ss * (1.f / DM) - mu * mu, 0.f);
    float rs = rsqrtf(var + 1e-3f);
    float4 ov;
    ov.x = (v[0] - mu) * rs * g[tid * 4 + 0] + be[tid * 4 + 0];
    ov.y = (v[1] - mu) * rs * g[tid * 4 + 1] + be[tid * 4 + 1];
    ov.z = (v[2] - mu) * rs * g[tid * 4 + 2] + be[tid * 4 + 2];
    ov.w = (v[3] - mu) * rs * g[tid * 4 + 3] + be[tid * 4 + 3];
    *(float4*)&outp[(size_t)row * DM + tid * 4] = ov;
}

extern "C" void kernel_launch(void* const* d_in, const int* in_sizes, int n_in,
                              void* d_out, int out_size, void* d_ws, size_t ws_size,
                              hipStream_t stream) {
    const float* x   = (const float*)d_in[0];
    const float* wts = (const float*)d_in[1];
    const float* Wq  = (const float*)d_in[2];
    const float* bq  = (const float*)d_in[3];
    const float* Wk  = (const float*)d_in[4];
    const float* bk  = (const float*)d_in[5];
    const float* Wv  = (const float*)d_in[6];
    const float* bv  = (const float*)d_in[7];
    const float* Wo  = (const float*)d_in[8];
    const float* bo  = (const float*)d_in[9];
    const float* W1  = (const float*)d_in[10];
    const float* b1  = (const float*)d_in[11];
    const float* W2  = (const float*)d_in[12];
    const float* b2  = (const float*)d_in[13];
    const float* g1  = (const float*)d_in[14];
    const float* be1 = (const float*)d_in[15];
    const float* g2  = (const float*)d_in[16];
    const float* be2 = (const float*)d_in[17];

    char* ws = (char*)d_ws;
    const size_t MB = 1u << 20;
    // Arena timeline (peak ~98.6 MB):
    //  [0,24)  qkv_bf (QKV->flash)        -> attnproj partials [0,32) (Oproj->ln1) -> ffn1_bf [0,32)
    //  [24,32) vt (QKV epilogue->flash)
    //  [32,40) x_bf (prep->QKV)           -> attn_bf (combine->Oproj) -> ffn2 partials [32,64)
    //  [40,46) wqkv_t, [46,48) Wo_t, [48,56) W1_t
    //  [64,98) po (flash->combine)        -> h_f32 [64,80), h_bf [80,88)
    //  [88,96) W2_t (written AFTER combine)
    //  [98,~)  pl, bqkv, logw
    unsigned short* qkv_bf  = (unsigned short*)(ws + 0 * MB);
    unsigned short* vt      = (unsigned short*)(ws + 24 * MB);
    unsigned short* x_bf    = (unsigned short*)(ws + 32 * MB);
    unsigned short* wqkv_t  = (unsigned short*)(ws + 40 * MB);
    unsigned short* Wo_t    = (unsigned short*)(ws + 46 * MB);
    unsigned short* W1_t    = (unsigned short*)(ws + 48 * MB);
    float* po               = (float*)(ws + 64 * MB);
    unsigned short* W2_t    = (unsigned short*)(ws + 88 * MB);
    float* pl               = (float*)(ws + 98 * MB);
    float* bqkv             = (float*)(ws + 98 * MB + 0x80000);
    float* logw             = (float*)(ws + 98 * MB + 0x88000);
    unsigned short* attn_bf = (unsigned short*)(ws + 32 * MB);
    float* attnproj         = (float*)(ws + 0 * MB);   // partials [0,16),[16,32)
    float* h_f32            = (float*)(ws + 64 * MB);
    unsigned short* h_bf    = (unsigned short*)(ws + 80 * MB);
    unsigned short* ffn1_bf = (unsigned short*)(ws + 0 * MB);
    float* ffn2             = (float*)(ws + 32 * MB);  // partials [32,48),[48,64)

    // 1. prep (2 launches; W2 transpose deferred until po is dead)
    prep_misc<<<4124, 256, 0, stream>>>(x, wts, bq, bk, bv, x_bf, logw, bqkv);
    prep_weights<<<8192, 256, 0, stream>>>(Wq, Wk, Wv, Wo, W1, wqkv_t, Wo_t, W1_t);

    // 2. fused QKV projection; V written directly transposed into vt
    gemm_kernel<128, false, 2, 1><<<dim3(QKVN / 128, MROWS / 128), 256, 0, stream>>>(
        x_bf, wqkv_t, bqkv, qkv_bf, vt, MROWS, QKVN, DM);

    // 3. attention (split-K over keys) + combine
    flash_kernel<<<dim3(SQL / 64, NB * NH, 2), 256, 0, stream>>>(qkv_bf, vt, logw, po, pl);
    combine_kernel<<<(32 * 2048 * 16) / 256, 256, 0, stream>>>(po, pl, attn_bf);

    // W2 transpose now that po ([64,98)) is dead; target [88,96)
    transpose_f32_bf16<<<dim3(32, 128), 256, 0, stream>>>(W2, W2_t, DFF, DM, 1.f);

    // 4. O projection (BN=128, split-K 2) + LN1
    gemm_kernel<128, false, 0, 2><<<dim3(DM / 128, MROWS / 128, 2), 256, 0, stream>>>(
        attn_bf, Wo_t, bo, attnproj, nullptr, MROWS, DM, DM);
    ln1_kernel<<<MROWS, 256, 0, stream>>>(x, attnproj, attnproj + (size_t)MROWS * DM,
                                          g1, be1, h_f32, h_bf);

    // 5. FFN (FFN2 BN=128 split-K 2) + LN2
    gemm_kernel<128, true, 1, 1><<<dim3(DFF / 128, MROWS / 128), 256, 0, stream>>>(
        h_bf, W1_t, b1, ffn1_bf, nullptr, MROWS, DFF, DM);
    gemm_kernel<128, false, 0, 2><<<dim3(DM / 128, MROWS / 128, 2), 256, 0, stream>>>(
        ffn1_bf, W2_t, b2, ffn2, nullptr, MROWS, DM, DFF);
    ln2_kernel<<<MROWS, 256, 0, stream>>>(h_f32, ffn2, ffn2 + (size_t)MROWS * DM,
                                          g2, be2, (float*)d_out);
}

// Round 8
// 356.655 us; speedup vs baseline: 1.1601x; 1.0824x over previous
//
#include <hip/hip_runtime.h>
#include <cstdint>
#include <cstddef>

#define DM 1024
#define NH 16
#define DKH 64
#define DFF 4096
#define NB 2
#define SQL 2048
#define MROWS (NB * SQL) /* 4096 */
#define QKVN 3072

typedef __attribute__((ext_vector_type(8))) __bf16 bf16x8;
typedef __attribute__((ext_vector_type(8))) short short8;
typedef __attribute__((ext_vector_type(4))) float f32x4;

__device__ __forceinline__ unsigned short f2bf(float f) {
    unsigned u = __float_as_uint(f);
    u += 0x7fffu + ((u >> 16) & 1u);
    return (unsigned short)(u >> 16);
}
__device__ __forceinline__ bf16x8 ldfrag(const unsigned short* p) {
    return __builtin_bit_cast(bf16x8, *(const short8*)p);
}
__device__ __forceinline__ void gl_lds16(const void* g, void* lds) {
    __builtin_amdgcn_global_load_lds(
        (const __attribute__((address_space(1))) unsigned int*)g,
        (__attribute__((address_space(3))) unsigned int*)lds, 16, 0, 0);
}
#define MFMA16(a, b, c) __builtin_amdgcn_mfma_f32_16x16x32_bf16(a, b, c, 0, 0, 0)

// ---------------- merged misc prep: x cast (4096 blks) + logw (16) + bqkv (12) ----------------
__global__ __launch_bounds__(256) void prep_misc(const float* __restrict__ x,
                                                 const float* __restrict__ wts,
                                                 const float* __restrict__ bq,
                                                 const float* __restrict__ bk,
                                                 const float* __restrict__ bv,
                                                 unsigned short* __restrict__ x_bf,
                                                 float* __restrict__ logw,
                                                 float* __restrict__ bqkv) {
    const int bid = blockIdx.x, tid = threadIdx.x;
    if (bid < 4096) {
        int i = (bid * 256 + tid) * 4;
        float4 v = *(const float4*)&x[i];
        ushort4 o;
        o.x = f2bf(v.x); o.y = f2bf(v.y); o.z = f2bf(v.z); o.w = f2bf(v.w);
        *(ushort4*)&x_bf[i] = o;
    } else if (bid < 4112) {
        int i = (bid - 4096) * 256 + tid;
        logw[i] = logf(wts[i] + 1e-20f);
    } else {
        int i = (bid - 4112) * 256 + tid;
        if (i < QKVN)
            bqkv[i] = i < 1024 ? bq[i] * 0.125f : (i < 2048 ? bk[i - 1024] : bv[i - 2048]);
    }
}

// ---------------- merged weight transposes: fp32 (K x N) -> bf16 (N x K) ----------------
// [0,1024) Wq (scale 1/8), [1024,2048) Wk, [2048,3072) Wv, [3072,4096) Wo,
// [4096,8192) W1, [8192,12288) W2
__global__ __launch_bounds__(256) void prep_weights(const float* __restrict__ Wq,
                                                    const float* __restrict__ Wk,
                                                    const float* __restrict__ Wv,
                                                    const float* __restrict__ Wo,
                                                    const float* __restrict__ W1,
                                                    const float* __restrict__ W2,
                                                    unsigned short* __restrict__ wqkv_t,
                                                    unsigned short* __restrict__ Wo_t,
                                                    unsigned short* __restrict__ W1_t,
                                                    unsigned short* __restrict__ W2_t) {
    __shared__ float tile[32][33];
    const int t = blockIdx.x;
    const float* in;
    unsigned short* out;
    int K = DM, N = DM, n0, k0;
    float scale = 1.f;
    if (t < 1024)      { in = Wq; out = wqkv_t;                      scale = 0.125f;
                         n0 = (t & 31) * 32;          k0 = (t >> 5) * 32; }
    else if (t < 2048) { in = Wk; out = wqkv_t + (size_t)1024 * DM;
                         n0 = ((t - 1024) & 31) * 32; k0 = ((t - 1024) >> 5) * 32; }
    else if (t < 3072) { in = Wv; out = wqkv_t + (size_t)2048 * DM;
                         n0 = ((t - 2048) & 31) * 32; k0 = ((t - 2048) >> 5) * 32; }
    else if (t < 4096) { in = Wo; out = Wo_t;
                         n0 = ((t - 3072) & 31) * 32; k0 = ((t - 3072) >> 5) * 32; }
    else if (t < 8192) { in = W1; out = W1_t; N = DFF;
                         n0 = ((t - 4096) & 127) * 32; k0 = ((t - 4096) >> 7) * 32; }
    else               { in = W2; out = W2_t; K = DFF;
                         n0 = ((t - 8192) & 31) * 32;  k0 = ((t - 8192) >> 5) * 32; }
    const int tx = threadIdx.x & 31, ty = threadIdx.x >> 5;
#pragma unroll
    for (int i = 0; i < 32; i += 8)
        tile[ty + i][tx] = in[(size_t)(k0 + ty + i) * N + n0 + tx];
    __syncthreads();
#pragma unroll
    for (int i = 0; i < 32; i += 8)
        out[(size_t)(n0 + ty + i) * K + k0 + tx] = f2bf(tile[tx][ty + i] * scale);
}

// ---------------- bf16 GEMM: C[M,N] = A[M,K] @ Wt[N,K]^T + bias ----------------
// 128 x BN tile, BK=64, global_load_lds 16B staging, XOR-swizzled 16B blocks.
// OMODE: 0 = fp32 partials (out + z*M*N), 1 = bf16 row-major, 2 = bf16 row-major for
//        col<2048 and V-transposed (vt[bh][d][s]) for col>=2048 (QKV fused epilogue).
template <int BN, bool RELU, int OMODE, int KSPL>
__global__ __launch_bounds__(256) void gemm_kernel(const unsigned short* __restrict__ A,
                                                   const unsigned short* __restrict__ Wt,
                                                   const float* __restrict__ bias,
                                                   void* __restrict__ outp,
                                                   unsigned short* __restrict__ vtp,
                                                   int M, int N, int K) {
    constexpr int NT = BN / 32;
    __shared__ unsigned short As[128 * 64];
    __shared__ unsigned short Bs[BN * 64];
    const int tid = threadIdx.x;
    const int wave = tid >> 6, lane = tid & 63;
    const int col16 = lane & 15, quad = lane >> 4;
    const int lrow = lane >> 3, sblk = (lane & 7) ^ (lrow & 7);
    const int m0 = blockIdx.y * 128, n0 = blockIdx.x * BN;
    const int wm = (wave >> 1) * 64, wn = (wave & 1) * (BN / 2);
    const int kbeg = (KSPL > 1) ? blockIdx.z * (K / KSPL) : 0;
    const int kend = kbeg + K / KSPL;

    f32x4 acc[4][NT] = {};

    for (int k0 = kbeg; k0 < kend; k0 += 64) {
        __syncthreads();
#pragma unroll
        for (int c = wave; c < 16; c += 4)
            gl_lds16(&A[(size_t)(m0 + c * 8 + lrow) * K + k0 + sblk * 8], &As[c * 512]);
#pragma unroll
        for (int c = wave; c < BN / 8; c += 4)
            gl_lds16(&Wt[(size_t)(n0 + c * 8 + lrow) * K + k0 + sblk * 8], &Bs[c * 512]);
        __syncthreads();
#pragma unroll
        for (int kk8 = 0; kk8 < 8; kk8 += 4) {
            bf16x8 af[4], bfr[NT];
#pragma unroll
            for (int t = 0; t < 4; ++t) {
                int R = wm + t * 16 + col16;
                af[t] = ldfrag(&As[R * 64 + (((kk8 + quad) ^ (R & 7)) << 3)]);
            }
#pragma unroll
            for (int t = 0; t < NT; ++t) {
                int R = wn + t * 16 + col16;
                bfr[t] = ldfrag(&Bs[R * 64 + (((kk8 + quad) ^ (R & 7)) << 3)]);
            }
#pragma unroll
            for (int mt = 0; mt < 4; ++mt)
#pragma unroll
                for (int nt = 0; nt < NT; ++nt)
                    acc[mt][nt] = MFMA16(af[mt], bfr[nt], acc[mt][nt]);
        }
    }

    float* outf = (float*)outp + ((KSPL > 1) ? (size_t)blockIdx.z * M * N : 0);
#pragma unroll
    for (int mt = 0; mt < 4; ++mt)
#pragma unroll
        for (int nt = 0; nt < NT; ++nt) {
            int col = n0 + wn + nt * 16 + col16;
            float bv = (KSPL == 1 || blockIdx.z == 0) ? bias[col] : 0.f;
            if (OMODE == 2 && col >= 2048) {
                // V tile: write transposed into vt[bh][d][s], packed over 4 consecutive s
                int dl = (col - 2048) & 63, hh = (col - 2048) >> 6;
                int row0 = m0 + wm + mt * 16 + quad * 4;
                int bb = row0 >> 11, sb = row0 & 2047;
                ushort4 w4;
                w4.x = f2bf(acc[mt][nt][0] + bv);
                w4.y = f2bf(acc[mt][nt][1] + bv);
                w4.z = f2bf(acc[mt][nt][2] + bv);
                w4.w = f2bf(acc[mt][nt][3] + bv);
                *(ushort4*)&vtp[(size_t)(bb * NH + hh) * DKH * SQL + (size_t)dl * SQL + sb] = w4;
            } else {
#pragma unroll
                for (int r = 0; r < 4; ++r) {
                    int row = m0 + wm + mt * 16 + quad * 4 + r;
                    float v = acc[mt][nt][r] + bv;
                    if (RELU) v = fmaxf(v, 0.f);
                    if (OMODE == 0)
                        outf[(size_t)row * N + col] = v;
                    else
                        ((unsigned short*)outp)[(size_t)row * N + col] = f2bf(v);
                }
            }
        }
}

// ---------------- flash attention: 8-wave blocks, 128 q-rows, direct bf16 out ----------------
// grid (SQL/128, NB*NH), block 512. Q pre-scaled 1/8. Per-wave body = R5-measured version.
__global__ __launch_bounds__(512) void flash_kernel(const unsigned short* __restrict__ qkv,
                                                    const unsigned short* __restrict__ vt,
                                                    const float* __restrict__ logw,
                                                    unsigned short* __restrict__ attn_bf) {
    __shared__ unsigned short Ks[64 * 64];
    __shared__ unsigned short Vt[64 * 64];
    __shared__ unsigned short Ps[8][16][72];
    __shared__ float lws[64];

    const int tid = threadIdx.x, wave = tid >> 6, lane = tid & 63;
    const int col16 = lane & 15, quad = lane >> 4;
    const int lrow = lane >> 3, sblk = (lane & 7) ^ (lrow & 7);
    const int bh = blockIdx.y, b = bh >> 4, h = bh & 15;
    const int q0 = blockIdx.x * 128;

    const unsigned short* Kg = qkv + (size_t)b * SQL * QKVN + 1024 + h * DKH;
    const unsigned short* Vg = vt + (size_t)bh * DKH * SQL;

    bf16x8 qf[2];
    {
        const unsigned short* qrow =
            qkv + (size_t)(b * SQL + q0 + wave * 16 + col16) * QKVN + h * DKH;
        qf[0] = ldfrag(qrow + quad * 8);
        qf[1] = ldfrag(qrow + 32 + quad * 8);
    }
    bf16x8 ones;
    {
        short8 o8 = {0x3f80, 0x3f80, 0x3f80, 0x3f80, 0x3f80, 0x3f80, 0x3f80, 0x3f80};
        ones = __builtin_bit_cast(bf16x8, o8);
    }

    f32x4 o[4] = {};
    f32x4 lacc = {};

    for (int kt = 0; kt < SQL; kt += 64) {
        __syncthreads();
        if (wave < 8) {
            int c = wave;
            gl_lds16(&Kg[(size_t)(kt + c * 8 + lrow) * QKVN + sblk * 8], &Ks[c * 512]);
            gl_lds16(&Vg[(size_t)(c * 8 + lrow) * SQL + kt + sblk * 8], &Vt[c * 512]);
        }
        if (tid < 64) lws[tid] = logw[b * SQL + kt + tid];
        __syncthreads();

        float pv[4][4];
#pragma unroll
        for (int nt = 0; nt < 4; ++nt) {
            int R = nt * 16 + col16;
            f32x4 s4 = {};
            s4 = MFMA16(qf[0], ldfrag(&Ks[R * 64 + ((quad ^ (R & 7)) << 3)]), s4);
            s4 = MFMA16(qf[1], ldfrag(&Ks[R * 64 + (((4 + quad) ^ (R & 7)) << 3)]), s4);
            float lw = lws[R];
#pragma unroll
            for (int r = 0; r < 4; ++r) pv[nt][r] = __expf(s4[r] + lw);
        }
#pragma unroll
        for (int nt = 0; nt < 4; ++nt)
#pragma unroll
            for (int r = 0; r < 4; ++r)
                Ps[wave][quad * 4 + r][nt * 16 + col16] = f2bf(pv[nt][r]);
        __syncthreads();

#pragma unroll
        for (int kk8 = 0; kk8 < 8; kk8 += 4) {
            bf16x8 psf = ldfrag(&Ps[wave][col16][(kk8 + quad) << 3]);
            lacc = MFMA16(ones, psf, lacc);
#pragma unroll
            for (int dt = 0; dt < 4; ++dt) {
                int R = dt * 16 + col16;
                bf16x8 vf = ldfrag(&Vt[R * 64 + (((kk8 + quad) ^ (R & 7)) << 3)]);
                o[dt] = MFMA16(vf, psf, o[dt]);
            }
        }
    }

    const float rl = 1.0f / lacc[0];
    const int qrow = b * SQL + q0 + wave * 16 + col16;
#pragma unroll
    for (int dt = 0; dt < 4; ++dt) {
        ushort4 h4;
        h4.x = f2bf(o[dt][0] * rl);
        h4.y = f2bf(o[dt][1] * rl);
        h4.z = f2bf(o[dt][2] * rl);
        h4.w = f2bf(o[dt][3] * rl);
        *(ushort4*)&attn_bf[(size_t)qrow * DM + h * DKH + dt * 16 + quad * 4] = h4;
    }
}

// ---------------- LN1: h = LN(x + d0 + d1); out fp32 + bf16 ----------------
__global__ __launch_bounds__(256) void ln1_kernel(const float* __restrict__ x,
                                                  const float* __restrict__ d0,
                                                  const float* __restrict__ d1,
                                                  const float* __restrict__ g,
                                                  const float* __restrict__ be,
                                                  float* __restrict__ hf,
                                                  unsigned short* __restrict__ hb) {
    const int row = blockIdx.x, tid = threadIdx.x;
    float4 xv = *(const float4*)&x[(size_t)row * DM + tid * 4];
    float4 av = *(const float4*)&d0[(size_t)row * DM + tid * 4];
    float4 bv = *(const float4*)&d1[(size_t)row * DM + tid * 4];
    float v[4] = {xv.x + av.x + bv.x, xv.y + av.y + bv.y, xv.z + av.z + bv.z,
                  xv.w + av.w + bv.w};
    float s = v[0] + v[1] + v[2] + v[3];
    float ss = v[0] * v[0] + v[1] * v[1] + v[2] * v[2] + v[3] * v[3];
#pragma unroll
    for (int m = 1; m < 64; m <<= 1) { s += __shfl_xor(s, m); ss += __shfl_xor(ss, m); }
    __shared__ float sb[4], ssb[4];
    if ((tid & 63) == 0) { sb[tid >> 6] = s; ssb[tid >> 6] = ss; }
    __syncthreads();
    s = sb[0] + sb[1] + sb[2] + sb[3];
    ss = ssb[0] + ssb[1] + ssb[2] + ssb[3];
    float mu = s * (1.f / DM);
    float var = fmaxf(ss * (1.f / DM) - mu * mu, 0.f);
    float rs = rsqrtf(var + 1e-3f);
#pragma unroll
    for (int i = 0; i < 4; ++i) {
        int c = tid * 4 + i;
        float y = (v[i] - mu) * rs * g[c] + be[c];
        hf[(size_t)row * DM + c] = y;
        hb[(size_t)row * DM + c] = f2bf(y);
    }
}

// ---------------- LN2: out = LN(h + d0 + d1) fp32 ----------------
__global__ __launch_bounds__(256) void ln2_kernel(const float* __restrict__ hf,
                                                  const float* __restrict__ d0,
                                                  const float* __restrict__ d1,
                                                  const float* __restrict__ g,
                                                  const float* __restrict__ be,
                                                  float* __restrict__ outp) {
    const int row = blockIdx.x, tid = threadIdx.x;
    float4 hv = *(const float4*)&hf[(size_t)row * DM + tid * 4];
    float4 av = *(const float4*)&d0[(size_t)row * DM + tid * 4];
    float4 bv = *(const float4*)&d1[(size_t)row * DM + tid * 4];
    float v[4] = {hv.x + av.x + bv.x, hv.y + av.y + bv.y, hv.z + av.z + bv.z,
                  hv.w + av.w + bv.w};
    float s = v[0] + v[1] + v[2] + v[3];
    float ss = v[0] * v[0] + v[1] * v[1] + v[2] * v[2] + v[3] * v[3];
#pragma unroll
    for (int m = 1; m < 64; m <<= 1) { s += __shfl_xor(s, m); ss += __shfl_xor(ss, m); }
    __shared__ float sb[4], ssb[4];
    if ((tid & 63) == 0) { sb[tid >> 6] = s; ssb[tid >> 6] = ss; }
    __syncthreads();
    s = sb[0] + sb[1] + sb[2] + sb[3];
    ss = ssb[0] + ssb[1] + ssb[2] + ssb[3];
    float mu = s * (1.f / DM);
    float var = fmaxf(ss * (1.f / DM) - mu * mu, 0.f);
    float rs = rsqrtf(var + 1e-3f);
    float4 ov;
    ov.x = (v[0] - mu) * rs * g[tid * 4 + 0] + be[tid * 4 + 0];
    ov.y = (v[1] - mu) * rs * g[tid * 4 + 1] + be[tid * 4 + 1];
    ov.z = (v[2] - mu) * rs * g[tid * 4 + 2] + be[tid * 4 + 2];
    ov.w = (v[3] - mu) * rs * g[tid * 4 + 3] + be[tid * 4 + 3];
    *(float4*)&outp[(size_t)row * DM + tid * 4] = ov;
}

extern "C" void kernel_launch(void* const* d_in, const int* in_sizes, int n_in,
                              void* d_out, int out_size, void* d_ws, size_t ws_size,
                              hipStream_t stream) {
    const float* x   = (const float*)d_in[0];
    const float* wts = (const float*)d_in[1];
    const float* Wq  = (const float*)d_in[2];
    const float* bq  = (const float*)d_in[3];
    const float* Wk  = (const float*)d_in[4];
    const float* bk  = (const float*)d_in[5];
    const float* Wv  = (const float*)d_in[6];
    const float* bv  = (const float*)d_in[7];
    const float* Wo  = (const float*)d_in[8];
    const float* bo  = (const float*)d_in[9];
    const float* W1  = (const float*)d_in[10];
    const float* b1  = (const float*)d_in[11];
    const float* W2  = (const float*)d_in[12];
    const float* b2  = (const float*)d_in[13];
    const float* g1  = (const float*)d_in[14];
    const float* be1 = (const float*)d_in[15];
    const float* g2  = (const float*)d_in[16];
    const float* be2 = (const float*)d_in[17];

    char* ws = (char*)d_ws;
    const size_t MB = 1u << 20;
    // Arena timeline (peak ~96.6 MB):
    //  [0,24)  qkv_bf (QKV->flash)     -> attnproj partials [0,32) (Oproj->ln1) -> ffn1_bf [0,32)
    //  [24,32) vt (QKV epilogue->flash)
    //  [32,40) x_bf (prep->QKV)        -> attn_bf (flash->Oproj) -> ffn2 partials [32,64)
    //  [40,46) wqkv_t, [46,48) Wo_t, [48,56) W1_t
    //  [64,80) h_f32, [80,88) h_bf (ln1->ln2)
    //  [88,96) W2_t (static)
    //  [96,~)  bqkv, logw
    unsigned short* qkv_bf  = (unsigned short*)(ws + 0 * MB);
    unsigned short* vt      = (unsigned short*)(ws + 24 * MB);
    unsigned short* x_bf    = (unsigned short*)(ws + 32 * MB);
    unsigned short* wqkv_t  = (unsigned short*)(ws + 40 * MB);
    unsigned short* Wo_t    = (unsigned short*)(ws + 46 * MB);
    unsigned short* W1_t    = (unsigned short*)(ws + 48 * MB);
    float* h_f32            = (float*)(ws + 64 * MB);
    unsigned short* h_bf    = (unsigned short*)(ws + 80 * MB);
    unsigned short* W2_t    = (unsigned short*)(ws + 88 * MB);
    float* bqkv             = (float*)(ws + 96 * MB);
    float* logw             = (float*)(ws + 96 * MB + 0x8000);
    unsigned short* attn_bf = (unsigned short*)(ws + 32 * MB);
    float* attnproj         = (float*)(ws + 0 * MB);   // partials [0,16),[16,32)
    unsigned short* ffn1_bf = (unsigned short*)(ws + 0 * MB);
    float* ffn2             = (float*)(ws + 32 * MB);  // partials [32,48),[48,64)

    // 1. prep (2 launches)
    prep_misc<<<4124, 256, 0, stream>>>(x, wts, bq, bk, bv, x_bf, logw, bqkv);
    prep_weights<<<12288, 256, 0, stream>>>(Wq, Wk, Wv, Wo, W1, W2,
                                            wqkv_t, Wo_t, W1_t, W2_t);

    // 2. fused QKV projection; V written directly transposed into vt
    gemm_kernel<128, false, 2, 1><<<dim3(QKVN / 128, MROWS / 128), 256, 0, stream>>>(
        x_bf, wqkv_t, bqkv, qkv_bf, vt, MROWS, QKVN, DM);

    // 3. attention (8-wave blocks, direct bf16 out)
    flash_kernel<<<dim3(SQL / 128, NB * NH), 512, 0, stream>>>(qkv_bf, vt, logw, attn_bf);

    // 4. O projection (BN=64, split-K 2) + LN1
    gemm_kernel<64, false, 0, 2><<<dim3(DM / 64, MROWS / 128, 2), 256, 0, stream>>>(
        attn_bf, Wo_t, bo, attnproj, nullptr, MROWS, DM, DM);
    ln1_kernel<<<MROWS, 256, 0, stream>>>(x, attnproj, attnproj + (size_t)MROWS * DM,
                                          g1, be1, h_f32, h_bf);

    // 5. FFN (FFN2 BN=64 split-K 2) + LN2
    gemm_kernel<128, true, 1, 1><<<dim3(DFF / 128, MROWS / 128), 256, 0, stream>>>(
        h_bf, W1_t, b1, ffn1_bf, nullptr, MROWS, DFF, DM);
    gemm_kernel<64, false, 0, 2><<<dim3(DM / 64, MROWS / 128, 2), 256, 0, stream>>>(
        ffn1_bf, W2_t, b2, ffn2, nullptr, MROWS, DM, DFF);
    ln2_kernel<<<MROWS, 256, 0, stream>>>(h_f32, ffn2, ffn2 + (size_t)MROWS * DM,
                                          g2, be2, (float*)d_out);
}

// Round 9
// 346.670 us; speedup vs baseline: 1.1935x; 1.0288x over previous
//
#include <hip/hip_runtime.h>
#include <cstdint>
#include <cstddef>

#define DM 1024
#define NH 16
#define DKH 64
#define DFF 4096
#define NB 2
#define SQL 2048
#define MROWS (NB * SQL) /* 4096 */
#define QKVN 3072

typedef __attribute__((ext_vector_type(8))) __bf16 bf16x8;
typedef __attribute__((ext_vector_type(8))) short short8;
typedef __attribute__((ext_vector_type(4))) float f32x4;

__device__ __forceinline__ unsigned short f2bf(float f) {
    unsigned u = __float_as_uint(f);
    u += 0x7fffu + ((u >> 16) & 1u);
    return (unsigned short)(u >> 16);
}
__device__ __forceinline__ bf16x8 ldfrag(const unsigned short* p) {
    return __builtin_bit_cast(bf16x8, *(const short8*)p);
}
__device__ __forceinline__ void gl_lds16(const void* g, void* lds) {
    __builtin_amdgcn_global_load_lds(
        (const __attribute__((address_space(1))) unsigned int*)g,
        (__attribute__((address_space(3))) unsigned int*)lds, 16, 0, 0);
}
#define MFMA16(a, b, c) __builtin_amdgcn_mfma_f32_16x16x32_bf16(a, b, c, 0, 0, 0)

// ---------------- merged prep: weight transposes + x cast + logw + bqkv ----------------
// [0,1024) Wq (scale 1/8), [1024,2048) Wk, [2048,3072) Wv, [3072,4096) Wo,
// [4096,8192) W1, [8192,12288) W2, [12288,16384) x cast, [16384,16400) logw, [16400,16412) bqkv
__global__ __launch_bounds__(256) void prep_all(const float* __restrict__ Wq,
                                                const float* __restrict__ Wk,
                                                const float* __restrict__ Wv,
                                                const float* __restrict__ Wo,
                                                const float* __restrict__ W1,
                                                const float* __restrict__ W2,
                                                const float* __restrict__ x,
                                                const float* __restrict__ wts,
                                                const float* __restrict__ bq,
                                                const float* __restrict__ bk,
                                                const float* __restrict__ bv,
                                                unsigned short* __restrict__ wqkv_t,
                                                unsigned short* __restrict__ Wo_t,
                                                unsigned short* __restrict__ W1_t,
                                                unsigned short* __restrict__ W2_t,
                                                unsigned short* __restrict__ x_bf,
                                                float* __restrict__ logw,
                                                float* __restrict__ bqkv) {
    const int t = blockIdx.x, tid = threadIdx.x;
    if (t >= 12288) {
        if (t < 16384) {
            int i = ((t - 12288) * 256 + tid) * 4;
            float4 v = *(const float4*)&x[i];
            ushort4 o;
            o.x = f2bf(v.x); o.y = f2bf(v.y); o.z = f2bf(v.z); o.w = f2bf(v.w);
            *(ushort4*)&x_bf[i] = o;
        } else if (t < 16400) {
            int i = (t - 16384) * 256 + tid;
            logw[i] = logf(wts[i] + 1e-20f);
        } else {
            int i = (t - 16400) * 256 + tid;
            if (i < QKVN)
                bqkv[i] = i < 1024 ? bq[i] * 0.125f : (i < 2048 ? bk[i - 1024] : bv[i - 2048]);
        }
        return;
    }
    __shared__ float tile[32][33];
    const float* in;
    unsigned short* out;
    int K = DM, N = DM, n0, k0;
    float scale = 1.f;
    if (t < 1024)      { in = Wq; out = wqkv_t;                      scale = 0.125f;
                         n0 = (t & 31) * 32;          k0 = (t >> 5) * 32; }
    else if (t < 2048) { in = Wk; out = wqkv_t + (size_t)1024 * DM;
                         n0 = ((t - 1024) & 31) * 32; k0 = ((t - 1024) >> 5) * 32; }
    else if (t < 3072) { in = Wv; out = wqkv_t + (size_t)2048 * DM;
                         n0 = ((t - 2048) & 31) * 32; k0 = ((t - 2048) >> 5) * 32; }
    else if (t < 4096) { in = Wo; out = Wo_t;
                         n0 = ((t - 3072) & 31) * 32; k0 = ((t - 3072) >> 5) * 32; }
    else if (t < 8192) { in = W1; out = W1_t; N = DFF;
                         n0 = ((t - 4096) & 127) * 32; k0 = ((t - 4096) >> 7) * 32; }
    else               { in = W2; out = W2_t; K = DFF;
                         n0 = ((t - 8192) & 31) * 32;  k0 = ((t - 8192) >> 5) * 32; }
    const int tx = threadIdx.x & 31, ty = threadIdx.x >> 5;
#pragma unroll
    for (int i = 0; i < 32; i += 8)
        tile[ty + i][tx] = in[(size_t)(k0 + ty + i) * N + n0 + tx];
    __syncthreads();
#pragma unroll
    for (int i = 0; i < 32; i += 8)
        out[(size_t)(n0 + ty + i) * K + k0 + tx] = f2bf(tile[tx][ty + i] * scale);
}

// ---------------- bf16 GEMM: C[M,N] = A[M,K] @ Wt[N,K]^T + bias ----------------
// 128 x BN tile, BK=64, global_load_lds 16B staging, XOR-swizzled 16B blocks.
// XCD swizzle: xcd = flat%8 owns gridDim.x/8 consecutive n-blocks (B L2-resident).
// OMODE: 0 = fp32 partials (out + z*M*N), 1 = bf16 row-major, 2 = bf16 row-major for
//        col<2048 and V-transposed (vt[bh][d][s]) for col>=2048 (QKV fused epilogue).
template <int BN, bool RELU, int OMODE, int KSPL>
__global__ __launch_bounds__(256) void gemm_kernel(const unsigned short* __restrict__ A,
                                                   const unsigned short* __restrict__ Wt,
                                                   const float* __restrict__ bias,
                                                   void* __restrict__ outp,
                                                   unsigned short* __restrict__ vtp,
                                                   int M, int N, int K) {
    constexpr int NT = BN / 32;
    __shared__ unsigned short As[128 * 64];
    __shared__ unsigned short Bs[BN * 64];
    const int tid = threadIdx.x;
    const int wave = tid >> 6, lane = tid & 63;
    const int col16 = lane & 15, quad = lane >> 4;
    const int lrow = lane >> 3, sblk = (lane & 7) ^ (lrow & 7);
    // XCD-aware block remap (gridDim.x assumed % 8 == 0)
    const int f = blockIdx.y * gridDim.x + blockIdx.x;
    const int nper = gridDim.x >> 3;
    const int bx = (f & 7) * nper + (f >> 3) % nper;
    const int by = (f >> 3) / nper;
    const int m0 = by * 128, n0 = bx * BN;
    const int wm = (wave >> 1) * 64, wn = (wave & 1) * (BN / 2);
    const int kbeg = (KSPL > 1) ? blockIdx.z * (K / KSPL) : 0;
    const int kend = kbeg + K / KSPL;

    f32x4 acc[4][NT] = {};

    for (int k0 = kbeg; k0 < kend; k0 += 64) {
        __syncthreads();
#pragma unroll
        for (int c = wave; c < 16; c += 4)
            gl_lds16(&A[(size_t)(m0 + c * 8 + lrow) * K + k0 + sblk * 8], &As[c * 512]);
#pragma unroll
        for (int c = wave; c < BN / 8; c += 4)
            gl_lds16(&Wt[(size_t)(n0 + c * 8 + lrow) * K + k0 + sblk * 8], &Bs[c * 512]);
        __syncthreads();
#pragma unroll
        for (int kk8 = 0; kk8 < 8; kk8 += 4) {
            bf16x8 af[4], bfr[NT];
#pragma unroll
            for (int t = 0; t < 4; ++t) {
                int R = wm + t * 16 + col16;
                af[t] = ldfrag(&As[R * 64 + (((kk8 + quad) ^ (R & 7)) << 3)]);
            }
#pragma unroll
            for (int t = 0; t < NT; ++t) {
                int R = wn + t * 16 + col16;
                bfr[t] = ldfrag(&Bs[R * 64 + (((kk8 + quad) ^ (R & 7)) << 3)]);
            }
#pragma unroll
            for (int mt = 0; mt < 4; ++mt)
#pragma unroll
                for (int nt = 0; nt < NT; ++nt)
                    acc[mt][nt] = MFMA16(af[mt], bfr[nt], acc[mt][nt]);
        }
    }

    float* outf = (float*)outp + ((KSPL > 1) ? (size_t)blockIdx.z * M * N : 0);
#pragma unroll
    for (int mt = 0; mt < 4; ++mt)
#pragma unroll
        for (int nt = 0; nt < NT; ++nt) {
            int col = n0 + wn + nt * 16 + col16;
            float bv = (KSPL == 1 || blockIdx.z == 0) ? bias[col] : 0.f;
            if (OMODE == 2 && col >= 2048) {
                // V tile: write transposed into vt[bh][d][s], packed over 4 consecutive s
                int dl = (col - 2048) & 63, hh = (col - 2048) >> 6;
                int row0 = m0 + wm + mt * 16 + quad * 4;
                int bb = row0 >> 11, sb = row0 & 2047;
                ushort4 w4;
                w4.x = f2bf(acc[mt][nt][0] + bv);
                w4.y = f2bf(acc[mt][nt][1] + bv);
                w4.z = f2bf(acc[mt][nt][2] + bv);
                w4.w = f2bf(acc[mt][nt][3] + bv);
                *(ushort4*)&vtp[(size_t)(bb * NH + hh) * DKH * SQL + (size_t)dl * SQL + sb] = w4;
            } else {
#pragma unroll
                for (int r = 0; r < 4; ++r) {
                    int row = m0 + wm + mt * 16 + quad * 4 + r;
                    float v = acc[mt][nt][r] + bv;
                    if (RELU) v = fmaxf(v, 0.f);
                    if (OMODE == 0)
                        outf[(size_t)row * N + col] = v;
                    else
                        ((unsigned short*)outp)[(size_t)row * N + col] = f2bf(v);
                }
            }
        }
}

// ---------------- flash attention: 8-wave blocks, 128 q-rows, direct bf16 out ----------------
// grid (16, 32), block 512. XCD swizzle: xcd owns bh in [4*xcd, 4*xcd+4) -> K/V L2-resident.
__global__ __launch_bounds__(512) void flash_kernel(const unsigned short* __restrict__ qkv,
                                                    const unsigned short* __restrict__ vt,
                                                    const float* __restrict__ logw,
                                                    unsigned short* __restrict__ attn_bf) {
    __shared__ unsigned short Ks[64 * 64];
    __shared__ unsigned short Vt[64 * 64];
    __shared__ unsigned short Ps[8][16][72];
    __shared__ float lws[64];

    const int tid = threadIdx.x, wave = tid >> 6, lane = tid & 63;
    const int col16 = lane & 15, quad = lane >> 4;
    const int lrow = lane >> 3, sblk = (lane & 7) ^ (lrow & 7);
    // XCD-aware remap: flat f -> xcd = f%8 handles bh = xcd*4 + (g%4), q-tile g/4
    const int f = blockIdx.y * gridDim.x + blockIdx.x;
    const int g = f >> 3;
    const int bh = (f & 7) * 4 + (g & 3);
    const int q0 = (g >> 2) * 128;
    const int b = bh >> 4, h = bh & 15;

    const unsigned short* Kg = qkv + (size_t)b * SQL * QKVN + 1024 + h * DKH;
    const unsigned short* Vg = vt + (size_t)bh * DKH * SQL;

    bf16x8 qf[2];
    {
        const unsigned short* qrow =
            qkv + (size_t)(b * SQL + q0 + wave * 16 + col16) * QKVN + h * DKH;
        qf[0] = ldfrag(qrow + quad * 8);
        qf[1] = ldfrag(qrow + 32 + quad * 8);
    }
    bf16x8 ones;
    {
        short8 o8 = {0x3f80, 0x3f80, 0x3f80, 0x3f80, 0x3f80, 0x3f80, 0x3f80, 0x3f80};
        ones = __builtin_bit_cast(bf16x8, o8);
    }

    f32x4 o[4] = {};
    f32x4 lacc = {};

    for (int kt = 0; kt < SQL; kt += 64) {
        __syncthreads();
        if (wave < 8) {
            int c = wave;
            gl_lds16(&Kg[(size_t)(kt + c * 8 + lrow) * QKVN + sblk * 8], &Ks[c * 512]);
            gl_lds16(&Vg[(size_t)(c * 8 + lrow) * SQL + kt + sblk * 8], &Vt[c * 512]);
        }
        if (tid < 64) lws[tid] = logw[b * SQL + kt + tid];
        __syncthreads();

        float pv[4][4];
#pragma unroll
        for (int nt = 0; nt < 4; ++nt) {
            int R = nt * 16 + col16;
            f32x4 s4 = {};
            s4 = MFMA16(qf[0], ldfrag(&Ks[R * 64 + ((quad ^ (R & 7)) << 3)]), s4);
            s4 = MFMA16(qf[1], ldfrag(&Ks[R * 64 + (((4 + quad) ^ (R & 7)) << 3)]), s4);
            float lw = lws[R];
#pragma unroll
            for (int r = 0; r < 4; ++r) pv[nt][r] = __expf(s4[r] + lw);
        }
#pragma unroll
        for (int nt = 0; nt < 4; ++nt)
#pragma unroll
            for (int r = 0; r < 4; ++r)
                Ps[wave][quad * 4 + r][nt * 16 + col16] = f2bf(pv[nt][r]);
        __syncthreads();

#pragma unroll
        for (int kk8 = 0; kk8 < 8; kk8 += 4) {
            bf16x8 psf = ldfrag(&Ps[wave][col16][(kk8 + quad) << 3]);
            lacc = MFMA16(ones, psf, lacc);
#pragma unroll
            for (int dt = 0; dt < 4; ++dt) {
                int R = dt * 16 + col16;
                bf16x8 vf = ldfrag(&Vt[R * 64 + (((kk8 + quad) ^ (R & 7)) << 3)]);
                o[dt] = MFMA16(vf, psf, o[dt]);
            }
        }
    }

    const float rl = 1.0f / lacc[0];
    const int qrow = b * SQL + q0 + wave * 16 + col16;
#pragma unroll
    for (int dt = 0; dt < 4; ++dt) {
        ushort4 h4;
        h4.x = f2bf(o[dt][0] * rl);
        h4.y = f2bf(o[dt][1] * rl);
        h4.z = f2bf(o[dt][2] * rl);
        h4.w = f2bf(o[dt][3] * rl);
        *(ushort4*)&attn_bf[(size_t)qrow * DM + h * DKH + dt * 16 + quad * 4] = h4;
    }
}

// ---------------- LN1: h = LN(x + d0 + d1); out fp32 + bf16 ----------------
__global__ __launch_bounds__(256) void ln1_kernel(const float* __restrict__ x,
                                                  const float* __restrict__ d0,
                                                  const float* __restrict__ d1,
                                                  const float* __restrict__ g,
                                                  const float* __restrict__ be,
                                                  float* __restrict__ hf,
                                                  unsigned short* __restrict__ hb) {
    const int row = blockIdx.x, tid = threadIdx.x;
    float4 xv = *(const float4*)&x[(size_t)row * DM + tid * 4];
    float4 av = *(const float4*)&d0[(size_t)row * DM + tid * 4];
    float4 bv = *(const float4*)&d1[(size_t)row * DM + tid * 4];
    float v[4] = {xv.x + av.x + bv.x, xv.y + av.y + bv.y, xv.z + av.z + bv.z,
                  xv.w + av.w + bv.w};
    float s = v[0] + v[1] + v[2] + v[3];
    float ss = v[0] * v[0] + v[1] * v[1] + v[2] * v[2] + v[3] * v[3];
#pragma unroll
    for (int m = 1; m < 64; m <<= 1) { s += __shfl_xor(s, m); ss += __shfl_xor(ss, m); }
    __shared__ float sb[4], ssb[4];
    if ((tid & 63) == 0) { sb[tid >> 6] = s; ssb[tid >> 6] = ss; }
    __syncthreads();
    s = sb[0] + sb[1] + sb[2] + sb[3];
    ss = ssb[0] + ssb[1] + ssb[2] + ssb[3];
    float mu = s * (1.f / DM);
    float var = fmaxf(ss * (1.f / DM) - mu * mu, 0.f);
    float rs = rsqrtf(var + 1e-3f);
#pragma unroll
    for (int i = 0; i < 4; ++i) {
        int c = tid * 4 + i;
        float y = (v[i] - mu) * rs * g[c] + be[c];
        hf[(size_t)row * DM + c] = y;
        hb[(size_t)row * DM + c] = f2bf(y);
    }
}

// ---------------- LN2: out = LN(h + d0 + d1) fp32 ----------------
__global__ __launch_bounds__(256) void ln2_kernel(const float* __restrict__ hf,
                                                  const float* __restrict__ d0,
                                                  const float* __restrict__ d1,
                                                  const float* __restrict__ g,
                                                  const float* __restrict__ be,
                                                  float* __restrict__ outp) {
    const int row = blockIdx.x, tid = threadIdx.x;
    float4 hv = *(const float4*)&hf[(size_t)row * DM + tid * 4];
    float4 av = *(const float4*)&d0[(size_t)row * DM + tid * 4];
    float4 bv = *(const float4*)&d1[(size_t)row * DM + tid * 4];
    float v[4] = {hv.x + av.x + bv.x, hv.y + av.y + bv.y, hv.z + av.z + bv.z,
                  hv.w + av.w + bv.w};
    float s = v[0] + v[1] + v[2] + v[3];
    float ss = v[0] * v[0] + v[1] * v[1] + v[2] * v[2] + v[3] * v[3];
#pragma unroll
    for (int m = 1; m < 64; m <<= 1) { s += __shfl_xor(s, m); ss += __shfl_xor(ss, m); }
    __shared__ float sb[4], ssb[4];
    if ((tid & 63) == 0) { sb[tid >> 6] = s; ssb[tid >> 6] = ss; }
    __syncthreads();
    s = sb[0] + sb[1] + sb[2] + sb[3];
    ss = ssb[0] + ssb[1] + ssb[2] + ssb[3];
    float mu = s * (1.f / DM);
    float var = fmaxf(ss * (1.f / DM) - mu * mu, 0.f);
    float rs = rsqrtf(var + 1e-3f);
    float4 ov;
    ov.x = (v[0] - mu) * rs * g[tid * 4 + 0] + be[tid * 4 + 0];
    ov.y = (v[1] - mu) * rs * g[tid * 4 + 1] + be[tid * 4 + 1];
    ov.z = (v[2] - mu) * rs * g[tid * 4 + 2] + be[tid * 4 + 2];
    ov.w = (v[3] - mu) * rs * g[tid * 4 + 3] + be[tid * 4 + 3];
    *(float4*)&outp[(size_t)row * DM + tid * 4] = ov;
}

extern "C" void kernel_launch(void* const* d_in, const int* in_sizes, int n_in,
                              void* d_out, int out_size, void* d_ws, size_t ws_size,
                              hipStream_t stream) {
    const float* x   = (const float*)d_in[0];
    const float* wts = (const float*)d_in[1];
    const float* Wq  = (const float*)d_in[2];
    const float* bq  = (const float*)d_in[3];
    const float* Wk  = (const float*)d_in[4];
    const float* bk  = (const float*)d_in[5];
    const float* Wv  = (const float*)d_in[6];
    const float* bv  = (const float*)d_in[7];
    const float* Wo  = (const float*)d_in[8];
    const float* bo  = (const float*)d_in[9];
    const float* W1  = (const float*)d_in[10];
    const float* b1  = (const float*)d_in[11];
    const float* W2  = (const float*)d_in[12];
    const float* b2  = (const float*)d_in[13];
    const float* g1  = (const float*)d_in[14];
    const float* be1 = (const float*)d_in[15];
    const float* g2  = (const float*)d_in[16];
    const float* be2 = (const float*)d_in[17];

    char* ws = (char*)d_ws;
    const size_t MB = 1u << 20;
    // Arena timeline (peak ~96.6 MB) — identical to R8:
    unsigned short* qkv_bf  = (unsigned short*)(ws + 0 * MB);
    unsigned short* vt      = (unsigned short*)(ws + 24 * MB);
    unsigned short* x_bf    = (unsigned short*)(ws + 32 * MB);
    unsigned short* wqkv_t  = (unsigned short*)(ws + 40 * MB);
    unsigned short* Wo_t    = (unsigned short*)(ws + 46 * MB);
    unsigned short* W1_t    = (unsigned short*)(ws + 48 * MB);
    float* h_f32            = (float*)(ws + 64 * MB);
    unsigned short* h_bf    = (unsigned short*)(ws + 80 * MB);
    unsigned short* W2_t    = (unsigned short*)(ws + 88 * MB);
    float* bqkv             = (float*)(ws + 96 * MB);
    float* logw             = (float*)(ws + 96 * MB + 0x8000);
    unsigned short* attn_bf = (unsigned short*)(ws + 32 * MB);
    float* attnproj         = (float*)(ws + 0 * MB);   // partials [0,16),[16,32)
    unsigned short* ffn1_bf = (unsigned short*)(ws + 0 * MB);
    float* ffn2             = (float*)(ws + 32 * MB);  // partials [32,48),[48,64)

    // 1. prep (single launch)
    prep_all<<<16412, 256, 0, stream>>>(Wq, Wk, Wv, Wo, W1, W2, x, wts, bq, bk, bv,
                                        wqkv_t, Wo_t, W1_t, W2_t, x_bf, logw, bqkv);

    // 2. fused QKV projection; V written directly transposed into vt
    gemm_kernel<128, false, 2, 1><<<dim3(QKVN / 128, MROWS / 128), 256, 0, stream>>>(
        x_bf, wqkv_t, bqkv, qkv_bf, vt, MROWS, QKVN, DM);

    // 3. attention (8-wave blocks, XCD-swizzled, direct bf16 out)
    flash_kernel<<<dim3(SQL / 128, NB * NH), 512, 0, stream>>>(qkv_bf, vt, logw, attn_bf);

    // 4. O projection (BN=64, split-K 2) + LN1
    gemm_kernel<64, false, 0, 2><<<dim3(DM / 64, MROWS / 128, 2), 256, 0, stream>>>(
        attn_bf, Wo_t, bo, attnproj, nullptr, MROWS, DM, DM);
    ln1_kernel<<<MROWS, 256, 0, stream>>>(x, attnproj, attnproj + (size_t)MROWS * DM,
                                          g1, be1, h_f32, h_bf);

    // 5. FFN (FFN2 BN=64 split-K 2) + LN2
    gemm_kernel<128, true, 1, 1><<<dim3(DFF / 128, MROWS / 128), 256, 0, stream>>>(
        h_bf, W1_t, b1, ffn1_bf, nullptr, MROWS, DFF, DM);
    gemm_kernel<64, false, 0, 2><<<dim3(DM / 64, MROWS / 128, 2), 256, 0, stream>>>(
        ffn1_bf, W2_t, b2, ffn2, nullptr, MROWS, DM, DFF);
    ln2_kernel<<<MROWS, 256, 0, stream>>>(h_f32, ffn2, ffn2 + (size_t)MROWS * DM,
                                          g2, be2, (float*)d_out);
}